// Round 3
// baseline (116.639 us; speedup 1.0000x reference)
//
#include <hip/hip_runtime.h>
#include <hip/hip_bf16.h>

// Problem constants (match reference setup_inputs)
#define BATCH 8
#define CHN   64
#define GRP   8
#define CG    8      // CHN / GRP
#define HH    128
#define WW    128
#define HW    (HH * WW)   // 16384
// w shape: (B, G, 1, 9, H, W); x/out shape: (B, C, H, W), all fp32.

// Each thread: one aligned float4 column-quad, 4 of the 8 channels in its group.
// tid bits = [b:3][g:3][c1:1][h:7][q:5] -> 524288 threads, 2048 blocks.
// c1 sits ABOVE h so each wave is still 2 rows x 32 quads (shuffle halo works),
// and the two blocks sharing the same w-tile are 16 apart in grid order (L2-hot).
__global__ __launch_bounds__(256, 6) void ska_small_kernel(
    const float* __restrict__ x,
    const float* __restrict__ wgt,
    float* __restrict__ out)
{
    int tid = blockIdx.x * blockDim.x + threadIdx.x;
    int q  = tid & 31;          // quad index within row
    int w0 = q * 4;             // aligned float4 column
    int h  = (tid >> 5) & 127;
    int c1 = (tid >> 12) & 1;   // which half of the channel group
    int g  = (tid >> 13) & 7;
    int b  = tid >> 16;

    // ---- 9 dynamic weights for this pixel-quad (shared across the 4 channels)
    const float* wbase = wgt + ((size_t)(b * GRP + g) * 9) * HW + (size_t)h * WW + w0;
    float4 wk[9];
#pragma unroll
    for (int k = 0; k < 9; ++k) {
        wk[k] = *(const float4*)(wbase + (size_t)k * HW);
    }

    // Fold vertical zero-padding into the weights (branchless).
    const float m_top = (h > 0)      ? 1.0f : 0.0f;
    const float m_bot = (h < HH - 1) ? 1.0f : 0.0f;
#pragma unroll
    for (int j = 0; j < 3; ++j) {
        wk[j].x     *= m_top; wk[j].y     *= m_top; wk[j].z     *= m_top; wk[j].w     *= m_top;
        wk[6 + j].x *= m_bot; wk[6 + j].y *= m_bot; wk[6 + j].z *= m_bot; wk[6 + j].w *= m_bot;
    }

    // Horizontal halo via neighbor-lane shuffle; mask the image pad columns.
    const float mL = (q > 0)  ? 1.0f : 0.0f;
    const float mR = (q < 31) ? 1.0f : 0.0f;

    // Clamped row indices (out-of-range rows are weight-masked to zero).
    const int hm = (h > 0)      ? h - 1 : h;
    const int hp = (h < HH - 1) ? h + 1 : h;

    const int c0 = g * CG + c1 * 4;
    const float* xbase = x   + (size_t)(b * CHN + c0) * HW + w0;
    float*       obase = out + (size_t)(b * CHN + c0) * HW + (size_t)h * WW + w0;

#pragma unroll
    for (int cg = 0; cg < 4; ++cg) {
        const float* xc = xbase + (size_t)cg * HW;
        float4 r0 = *(const float4*)(xc + (size_t)hm * WW);
        float4 r1 = *(const float4*)(xc + (size_t)h  * WW);
        float4 r2 = *(const float4*)(xc + (size_t)hp * WW);

        // 6-wide row windows: [left, v.x, v.y, v.z, v.w, right]
        float xr[3][6];
        xr[0][1] = r0.x; xr[0][2] = r0.y; xr[0][3] = r0.z; xr[0][4] = r0.w;
        xr[1][1] = r1.x; xr[1][2] = r1.y; xr[1][3] = r1.z; xr[1][4] = r1.w;
        xr[2][1] = r2.x; xr[2][2] = r2.y; xr[2][3] = r2.z; xr[2][4] = r2.w;
        xr[0][0] = __shfl_up(r0.w, 1) * mL;
        xr[1][0] = __shfl_up(r1.w, 1) * mL;
        xr[2][0] = __shfl_up(r2.w, 1) * mL;
        xr[0][5] = __shfl_down(r0.x, 1) * mR;
        xr[1][5] = __shfl_down(r1.x, 1) * mR;
        xr[2][5] = __shfl_down(r2.x, 1) * mR;

        float4 acc = make_float4(0.f, 0.f, 0.f, 0.f);
#pragma unroll
        for (int ki = 0; ki < 3; ++ki) {
#pragma unroll
            for (int kj = 0; kj < 3; ++kj) {
                const float4 wv = wk[ki * 3 + kj];
                acc.x = fmaf(xr[ki][0 + kj], wv.x, acc.x);
                acc.y = fmaf(xr[ki][1 + kj], wv.y, acc.y);
                acc.z = fmaf(xr[ki][2 + kj], wv.z, acc.z);
                acc.w = fmaf(xr[ki][3 + kj], wv.w, acc.w);
            }
        }

        *(float4*)(obase + (size_t)cg * HW) = acc;
    }
}

extern "C" void kernel_launch(void* const* d_in, const int* in_sizes, int n_in,
                              void* d_out, int out_size, void* d_ws, size_t ws_size,
                              hipStream_t stream) {
    const float* x = (const float*)d_in[0];
    const float* w = (const float*)d_in[1];
    float* out = (float*)d_out;

    // total threads = B * G * 2 * H * (W/4) = 524288
    const int total = BATCH * GRP * 2 * HH * (WW / 4);
    const int block = 256;
    const int grid = total / block;   // 2048
    ska_small_kernel<<<grid, block, 0, stream>>>(x, w, out);
}

// Round 4
// 105.426 us; speedup vs baseline: 1.1064x; 1.1064x over previous
//
#include <hip/hip_runtime.h>
#include <hip/hip_bf16.h>

// Problem constants (match reference setup_inputs)
#define BATCH 8
#define CHN   64
#define GRP   8
#define CG    8      // CHN / GRP
#define HH    128
#define WW    128
#define HW    (HH * WW)   // 16384
// w shape: (B, G, 1, 9, H, W); x/out shape: (B, C, H, W), all fp32.

// Each thread: 2 consecutive output rows x one aligned float4 quad x all 8
// channels of its group. tid bits = [b:3][g:3][h2:6][q:5] -> 131072 threads,
// 512 blocks. A wave = 2 thread-rows x 32 quads; halo via +-1 lane shuffle,
// masked at quad 0/31 (also masks the cross-segment shuffle at lane 32).
__global__ __launch_bounds__(256, 3) void ska_small_kernel(
    const float* __restrict__ x,
    const float* __restrict__ wgt,
    float* __restrict__ out)
{
    int tid = blockIdx.x * blockDim.x + threadIdx.x;
    int q  = tid & 31;           // quad index within row
    int w0 = q * 4;              // aligned float4 column
    int h2 = (tid >> 5) & 63;    // row-pair index
    int g  = (tid >> 11) & 7;
    int b  = tid >> 14;

    const int h0 = h2 * 2;       // even, 0..126
    const int h1 = h0 + 1;       // odd, 1..127

    // ---- 9 dynamic weights for each of the two pixel rows (shared across 8 ch)
    const float* wbase = wgt + ((size_t)(b * GRP + g) * 9) * HW + (size_t)h0 * WW + w0;
    float4 wk0[9], wk1[9];
#pragma unroll
    for (int k = 0; k < 9; ++k) {
        wk0[k] = *(const float4*)(wbase + (size_t)k * HW);
        wk1[k] = *(const float4*)(wbase + (size_t)k * HW + WW);
    }

    // Fold vertical zero-padding into the weights (branchless).
    const float m_top = (h0 > 0)      ? 1.0f : 0.0f;   // row h0's tap-row 0
    const float m_bot = (h1 < HH - 1) ? 1.0f : 0.0f;   // row h1's tap-row 2
#pragma unroll
    for (int j = 0; j < 3; ++j) {
        wk0[j].x     *= m_top; wk0[j].y     *= m_top; wk0[j].z     *= m_top; wk0[j].w     *= m_top;
        wk1[6 + j].x *= m_bot; wk1[6 + j].y *= m_bot; wk1[6 + j].z *= m_bot; wk1[6 + j].w *= m_bot;
    }

    // Horizontal halo via neighbor-lane shuffle; mask the image pad columns.
    const float mL = (q > 0)  ? 1.0f : 0.0f;
    const float mR = (q < 31) ? 1.0f : 0.0f;

    // Clamped outer row indices (out-of-range rows are weight-masked to zero).
    const int hm = (h0 > 0)      ? h0 - 1 : h0;
    const int hp = (h1 < HH - 1) ? h1 + 1 : h1;

    const float* xbase = x   + (size_t)(b * CHN + g * CG) * HW + w0;
    float*       obase = out + (size_t)(b * CHN + g * CG) * HW + (size_t)h0 * WW + w0;

#pragma unroll
    for (int cg = 0; cg < CG; ++cg) {
        const float* xc = xbase + (size_t)cg * HW;
        float4 rm = *(const float4*)(xc + (size_t)hm * WW);
        float4 r0 = *(const float4*)(xc + (size_t)h0 * WW);
        float4 r1 = *(const float4*)(xc + (size_t)h1 * WW);
        float4 rp = *(const float4*)(xc + (size_t)hp * WW);

        // 6-wide row windows: [left, v.x, v.y, v.z, v.w, right] for 4 rows
        float win[4][6];
        win[0][1] = rm.x; win[0][2] = rm.y; win[0][3] = rm.z; win[0][4] = rm.w;
        win[1][1] = r0.x; win[1][2] = r0.y; win[1][3] = r0.z; win[1][4] = r0.w;
        win[2][1] = r1.x; win[2][2] = r1.y; win[2][3] = r1.z; win[2][4] = r1.w;
        win[3][1] = rp.x; win[3][2] = rp.y; win[3][3] = rp.z; win[3][4] = rp.w;
        win[0][0] = __shfl_up(rm.w, 1) * mL;
        win[1][0] = __shfl_up(r0.w, 1) * mL;
        win[2][0] = __shfl_up(r1.w, 1) * mL;
        win[3][0] = __shfl_up(rp.w, 1) * mL;
        win[0][5] = __shfl_down(rm.x, 1) * mR;
        win[1][5] = __shfl_down(r0.x, 1) * mR;
        win[2][5] = __shfl_down(r1.x, 1) * mR;
        win[3][5] = __shfl_down(rp.x, 1) * mR;

        float4 acc0 = make_float4(0.f, 0.f, 0.f, 0.f);  // output row h0: rows m,0,1
        float4 acc1 = make_float4(0.f, 0.f, 0.f, 0.f);  // output row h1: rows 0,1,p
#pragma unroll
        for (int ki = 0; ki < 3; ++ki) {
#pragma unroll
            for (int kj = 0; kj < 3; ++kj) {
                const float4 wv0 = wk0[ki * 3 + kj];
                const float4 wv1 = wk1[ki * 3 + kj];
                acc0.x = fmaf(win[ki    ][0 + kj], wv0.x, acc0.x);
                acc0.y = fmaf(win[ki    ][1 + kj], wv0.y, acc0.y);
                acc0.z = fmaf(win[ki    ][2 + kj], wv0.z, acc0.z);
                acc0.w = fmaf(win[ki    ][3 + kj], wv0.w, acc0.w);
                acc1.x = fmaf(win[ki + 1][0 + kj], wv1.x, acc1.x);
                acc1.y = fmaf(win[ki + 1][1 + kj], wv1.y, acc1.y);
                acc1.z = fmaf(win[ki + 1][2 + kj], wv1.z, acc1.z);
                acc1.w = fmaf(win[ki + 1][3 + kj], wv1.w, acc1.w);
            }
        }

        *(float4*)(obase + (size_t)cg * HW)      = acc0;
        *(float4*)(obase + (size_t)cg * HW + WW) = acc1;
    }
}

extern "C" void kernel_launch(void* const* d_in, const int* in_sizes, int n_in,
                              void* d_out, int out_size, void* d_ws, size_t ws_size,
                              hipStream_t stream) {
    const float* x = (const float*)d_in[0];
    const float* w = (const float*)d_in[1];
    float* out = (float*)d_out;

    // total threads = B * G * (H/2) * (W/4) = 131072
    const int total = BATCH * GRP * (HH / 2) * (WW / 4);
    const int block = 256;
    const int grid = total / block;   // 512
    ska_small_kernel<<<grid, block, 0, stream>>>(x, w, out);
}